// Round 1
// baseline (260.721 us; speedup 1.0000x reference)
//
#include <hip/hip_runtime.h>

#define B_ROWS 4096
#define N_COLS 8192
#define BLOCK  256
#define VPT    (N_COLS / 4 / BLOCK)   // float4 loads per thread per input = 8

// Native clang vector type: __builtin_nontemporal_load requires a pointer to
// scalar/vector-of-scalar, not HIP's HIP_vector_type struct.
typedef float vfloat4 __attribute__((ext_vector_type(4)));

// R6 theory: rocprof top-5 shows row_pearson_kernel per-dispatch < 77 us
// (absent from the table; 512 MiB poison fills at 6.9 TB/s occupy all five
// slots), so ~170 us of dur_us is a fixed harness floor. The remaining
// kernel-side inefficiency: NT loads on BOTH inputs defeat labels' L3
// residency (nt = no-allocate, so labels can never re-claim L3 after the
// per-iteration poison fill evicts it). Asymmetric caching:
//   preds  -> nontemporal (pure HBM stream, no L3 allocation/eviction)
//   labels -> normal cached loads (128 MiB, fits and stays in 256 MiB L3)
// Expected: preds 128 MiB @ ~6.3 TB/s HBM overlapped with labels 128 MiB of
// L3 hits; kernel ~35-50 us. FETCH_SIZE stays ~= one input (preds only).
__global__ __launch_bounds__(BLOCK) void row_pearson_kernel(
    const float* __restrict__ preds,
    const float* __restrict__ labels,
    float* __restrict__ row_loss)
{
    const int row = blockIdx.x;
    const int tid = threadIdx.x;

    const vfloat4* p4 = reinterpret_cast<const vfloat4*>(preds  + (size_t)row * N_COLS);
    const vfloat4* l4 = reinterpret_cast<const vfloat4*>(labels + (size_t)row * N_COLS);

    float sx = 0.f, sy = 0.f, sxy = 0.f, sxx = 0.f, syy = 0.f;

    #pragma unroll
    for (int i = 0; i < VPT; ++i) {
        const vfloat4 x = __builtin_nontemporal_load(p4 + tid + i * BLOCK); // preds: stream
        const vfloat4 y = l4[tid + i * BLOCK];                              // labels: cached
        sx  += x.x + x.y + x.z + x.w;
        sy  += y.x + y.y + y.z + y.w;
        sxy += x.x * y.x + x.y * y.y + x.z * y.z + x.w * y.w;
        sxx += x.x * x.x + x.y * x.y + x.z * x.z + x.w * x.w;
        syy += y.x * y.x + y.y * y.y + y.z * y.z + y.w * y.w;
    }

    // 64-lane wave reduction (wave = 64 on gfx950).
    #pragma unroll
    for (int off = 32; off > 0; off >>= 1) {
        sx  += __shfl_down(sx,  off);
        sy  += __shfl_down(sy,  off);
        sxy += __shfl_down(sxy, off);
        sxx += __shfl_down(sxx, off);
        syy += __shfl_down(syy, off);
    }

    __shared__ float smem[4][5];   // 4 waves per block
    const int wave = tid >> 6;
    const int lane = tid & 63;
    if (lane == 0) {
        smem[wave][0] = sx;  smem[wave][1] = sy;  smem[wave][2] = sxy;
        smem[wave][3] = sxx; smem[wave][4] = syy;
    }
    __syncthreads();

    if (tid == 0) {
        float tx = 0.f, ty = 0.f, txy = 0.f, txx = 0.f, tyy = 0.f;
        #pragma unroll
        for (int w = 0; w < BLOCK / 64; ++w) {
            tx  += smem[w][0]; ty  += smem[w][1]; txy += smem[w][2];
            txx += smem[w][3]; tyy += smem[w][4];
        }
        const float Nf  = (float)N_COLS;
        const float num = Nf * txy - tx * ty;
        const float den = sqrtf((Nf * txx - tx * tx) * (Nf * tyy - ty * ty));
        row_loss[row] = 1.0f - num / den;
    }
}

// Reduce 4096 per-row losses to the mean. Single block.
__global__ __launch_bounds__(BLOCK) void mean_kernel(
    const float* __restrict__ row_loss,
    float* __restrict__ out)
{
    const int tid = threadIdx.x;

    float s = 0.f;
    #pragma unroll
    for (int i = 0; i < B_ROWS / BLOCK; ++i)
        s += row_loss[tid + i * BLOCK];

    #pragma unroll
    for (int off = 32; off > 0; off >>= 1)
        s += __shfl_down(s, off);

    __shared__ float smem[4];
    const int wave = tid >> 6;
    const int lane = tid & 63;
    if (lane == 0) smem[wave] = s;
    __syncthreads();

    if (tid == 0) {
        float t = smem[0] + smem[1] + smem[2] + smem[3];
        out[0] = t / (float)B_ROWS;
    }
}

extern "C" void kernel_launch(void* const* d_in, const int* in_sizes, int n_in,
                              void* d_out, int out_size, void* d_ws, size_t ws_size,
                              hipStream_t stream) {
    const float* preds  = (const float*)d_in[0];
    const float* labels = (const float*)d_in[1];
    float* row_loss = (float*)d_ws;      // 4096 floats of scratch
    float* out      = (float*)d_out;

    row_pearson_kernel<<<B_ROWS, BLOCK, 0, stream>>>(preds, labels, row_loss);
    mean_kernel<<<1, BLOCK, 0, stream>>>(row_loss, out);
}